// Round 15
// baseline (253.015 us; speedup 1.0000x reference)
//
#include <hip/hip_runtime.h>
#include <hip/hip_bf16.h>

#define N_TOK 131072
#define NE 8
#define NOUT 10
#define BM 32
#define TAU 1e-4f

typedef float f32x4 __attribute__((ext_vector_type(4)));
typedef float f32x16 __attribute__((ext_vector_type(16)));
typedef __bf16 bf16x8 __attribute__((ext_vector_type(8)));
typedef unsigned short u16;
typedef unsigned short u16x8 __attribute__((ext_vector_type(8)));

// ws layout (bytes): mandatory ~6.8MB (< proven-safe 7.9MB)
static constexpr size_t O_CNT  = 0;                                // cnt[8]
static constexpr size_t O_RG   = 256;                              // N*8
static constexpr size_t O_LIST = O_RG + (size_t)N_TOK*8;           // 8N*4 sparse segs
static constexpr size_t O_W1   = O_LIST + 8ull*N_TOK*4;            // 1MB
static constexpr size_t O_W2   = O_W1 + 8ull*256*256*2;            // 512KB
static constexpr size_t O_W3   = O_W2 + 8ull*128*256*2;            // 64KB
static constexpr size_t O_W1G  = O_W3 + 8ull*32*128*2;             // 128KB

static __device__ __forceinline__ u16 f2bf(float f) {
  union { float f; unsigned u; } v; v.f = f;
  unsigned r = v.u + 0x7FFFu + ((v.u >> 16) & 1u);
  return (u16)(r >> 16);
}
static __device__ __forceinline__ float bf2f(u16 h) {
  union { unsigned u; float f; } v; v.u = ((unsigned)h) << 16;
  return v.f;
}
static __device__ __forceinline__ unsigned cvtpk(float lo, float hi) {
  unsigned r;
  asm("v_cvt_pk_bf16_f32 %0, %1, %2" : "=v"(r) : "v"(lo), "v"(hi));
  return r;
}
// DPP partial sums. dppadd: single VALU add with DPP operand modifier.
template<int CTRL>
static __device__ __forceinline__ float dppadd(float v) {
  int p = __builtin_amdgcn_update_dpp(0, __float_as_int(v), CTRL, 0xF, 0xF, true);
  return v + __int_as_float(p);
}
// red16: sum within each 16-lane DPP row — pure VALU, no LDS ops.
static __device__ __forceinline__ float red16(float v) {
  v = dppadd<0xB1>(v);    // quad_perm [1,0,3,2]  (xor 1)
  v = dppadd<0x4E>(v);    // quad_perm [2,3,0,1]  (xor 2)
  v = dppadd<0x124>(v);   // row_ror:4
  v = dppadd<0x128>(v);   // row_ror:8  -> all 16 lanes hold 16-group sum
  return v;
}
// red32: full 32-lane sum (gate only; one ds_swizzle)
static __device__ __forceinline__ float red32(float v) {
  v = red16(v);
  int s = __builtin_amdgcn_ds_swizzle(__float_as_int(v), 0x401F); // xor 16
  return v + __int_as_float(s);
}
static __device__ __forceinline__ float gelu_erf(float v) {
  return 0.5f * v * (1.0f + erff(v * 0.70710678118654752440f));
}
// 4-term A&S 7.1.26 (|erf err|<=1.5e-7) — gate LN epilogue (routing-sensitive)
static __device__ __forceinline__ float gelu_fast(float v) {
  float s = fabsf(v) * 0.70710678118654752440f;
  float t = __builtin_amdgcn_rcpf(fmaf(0.3275911f, s, 1.0f));
  float p = t * fmaf(t, fmaf(t, fmaf(t, fmaf(t, 1.061405429f, -1.453152027f),
                                     1.421413741f), -0.284496736f), 0.254829592f);
  float e = __builtin_amdgcn_exp2f(s * s * -1.44269504088896f);
  float erfa = fmaf(-p, e, 1.0f);
  return fmaf(0.5f * fabsf(v), erfa, 0.5f * v);
}
// 3-term A&S 7.1.25 (|erf err|<=2.5e-5 << bf16 noise) — expert only
static __device__ __forceinline__ float gelu_fast3(float v) {
  float s = fabsf(v) * 0.70710678118654752440f;
  float t = __builtin_amdgcn_rcpf(fmaf(0.47047f, s, 1.0f));
  float p = t * fmaf(t, fmaf(t, 0.7478556f, -0.0958798f), 0.3480242f);
  float e = __builtin_amdgcn_exp2f(s * s * -1.44269504088896f);
  float erfa = fmaf(-p, e, 1.0f);
  return fmaf(0.5f * fabsf(v), erfa, 0.5f * v);
}

// ---- weight prep: fp32 -> bf16 per-MFMA fragment streams --------------------
__global__ __launch_bounds__(256) void prep_kernel(
    const float* __restrict__ eW1, const float* __restrict__ eW2,
    const float* __restrict__ eW3, const float* __restrict__ gW1,
    u16* __restrict__ w1f, u16* __restrict__ w2f, u16* __restrict__ w3f,
    u16* __restrict__ w1g)
{
  int id = blockIdx.x * 256 + threadIdx.x;
  u16x8 pk;
  if (id < 65536) {                       // expert W1: 8e x 8nt x 16ks x 64l
    int e = id >> 13, rem = id & 8191;
    int l = rem & 63;
    int n = ((rem >> 10) & 7)*32 + (l & 31);
    int k0 = (((rem >> 6) & 15)*2 + (l >> 5)) * 8;
#pragma unroll
    for (int j = 0; j < 8; ++j) pk[j] = f2bf(eW1[((size_t)(e*256 + k0 + j))*256 + n]);
    *(u16x8*)(w1f + (size_t)id*8) = pk;
  } else if (id < 98304) {                // expert W2: 8e x 4nt x 16ks x 64l
    int id2 = id - 65536;
    int e = id2 >> 12, rem = id2 & 4095;
    int l = rem & 63;
    int n = ((rem >> 10) & 3)*32 + (l & 31);
    int k0 = (((rem >> 6) & 15)*2 + (l >> 5)) * 8;
#pragma unroll
    for (int j = 0; j < 8; ++j) pk[j] = f2bf(eW2[((size_t)(e*256 + k0 + j))*128 + n]);
    *(u16x8*)(w2f + (size_t)id2*8) = pk;
  } else if (id < 102400) {               // expert W3 padded: 8e x 8ks x 64l
    int id3 = id - 98304;
    int e = id3 >> 9, ks = (id3 >> 6) & 7, l = id3 & 63;
    int n = l & 31;
    int k0 = (ks*2 + (l >> 5)) * 8;
#pragma unroll
    for (int j = 0; j < 8; ++j) {
      float v = (n < 10) ? eW3[((size_t)(e*128 + k0 + j))*10 + n] : 0.f;
      pk[j] = f2bf(v);
    }
    *(u16x8*)(w3f + (size_t)id3*8) = pk;
  } else {                                // gate W1 split hi/lo
    int id4 = id - 102400;                // 8192 ids
    int gp = id4 & 7, r = (id4 >> 3) & 127, c = (id4 >> 10) & 3, pl = id4 >> 12;
    int k0 = c*64 + ((gp ^ (r & 7)) * 8);
#pragma unroll
    for (int j = 0; j < 8; ++j) {
      float v = gW1[(size_t)(k0 + j)*128 + r];
      u16 hi = f2bf(v);
      if (pl == 0) pk[j] = hi;
      else         pk[j] = f2bf(v - bf2f(hi));
    }
    *(u16x8*)(w1g + ((size_t)(pl*4 + c)*128 + r)*64 + gp*8) = pk;
  }
}

// ---- gate: split-bf16 MFMA + LN + gelu + logits + top2 + in-block refine ----
__global__ __launch_bounds__(512) void gate_kernel(
    const float* __restrict__ x, const u16* __restrict__ w1g,
    const float* __restrict__ gW1,
    const float* __restrict__ gb1, const float* __restrict__ glng,
    const float* __restrict__ glnb, const float* __restrict__ gW2,
    const float* __restrict__ gb2v, const float* __restrict__ temp,
    float2* __restrict__ rg, int* __restrict__ cnt, int* __restrict__ list)
{
  extern __shared__ char gsm[];
  char* aHi = gsm;                        // [256 rows][8 gran][16B] 32KB
  char* aLo = gsm + 32768;
  char* wHi = gsm + 65536;                // [128 rows][8 gran][16B] 16KB
  char* wLo = gsm + 81920;
  char* gReg = gsm;                       // logits phase: [256][32 gran][16B] 128KB
  float* scr = (float*)(gsm + 131072);    // [256][20]
  float* w2l = (float*)(gsm + 151552);    // [128][8] = 4KB (reused by refine arrays)
  int*    refN = (int*)(gsm + 151552);    // after logits: refine scratch
  int*    refl = (int*)(gsm + 151560);    // [256]
  float2* refG = (float2*)(gsm + 152584); // [256]
  __shared__ int lh[8], gbase[8];

  const int tid = threadIdx.x;
  const int n0 = blockIdx.x * 256;
  const int w = tid >> 6, l = tid & 63;
  const int l31 = l & 31, lh5 = l >> 5;

  for (int i = tid; i < 1024; i += 512) w2l[i] = gW2[i];

  f32x16 acc[4];
#pragma unroll
  for (int nt = 0; nt < 4; ++nt) acc[nt] = (f32x16)0.f;

  const int rowA = w*32 + l31;
  const int swA = rowA & 7;

  for (int c = 0; c < 4; ++c) {
    __syncthreads();
#pragma unroll
    for (int it = 0; it < 4; ++it) {
      int G = tid + 512*it;
      int row = G >> 3, g = G & 7;
      const float* src = x + (size_t)(n0 + row)*256 + c*64 + g*8;
      f32x4 va = *(const f32x4*)src;
      f32x4 vb = *(const f32x4*)(src + 4);
      u16x8 hi, lo;
#pragma unroll
      for (int i = 0; i < 4; ++i) {
        u16 h = f2bf(va[i]); hi[i] = h; lo[i] = f2bf(va[i] - bf2f(h));
      }
#pragma unroll
      for (int i = 0; i < 4; ++i) {
        u16 h = f2bf(vb[i]); hi[4+i] = h; lo[4+i] = f2bf(vb[i] - bf2f(h));
      }
      int off = row*128 + ((g ^ (row & 7)) << 4);
      *(u16x8*)(aHi + off) = hi;
      *(u16x8*)(aLo + off) = lo;
    }
    {
      const u16* srcH = w1g + (size_t)c*8192;
      const u16* srcL = w1g + (size_t)(4 + c)*8192;
#pragma unroll
      for (int it = 0; it < 2; ++it) {
        int i = tid + 512*it;
        *(u16x8*)(wHi + i*16) = *(const u16x8*)(srcH + i*8);
        *(u16x8*)(wLo + i*16) = *(const u16x8*)(srcL + i*8);
      }
    }
    __syncthreads();
#pragma unroll
    for (int ks = 0; ks < 4; ++ks) {
      int gk = ks*2 + lh5;
      bf16x8 afH = *(const bf16x8*)(aHi + rowA*128 + ((gk ^ swA) << 4));
      bf16x8 afL = *(const bf16x8*)(aLo + rowA*128 + ((gk ^ swA) << 4));
#pragma unroll
      for (int nt = 0; nt < 4; ++nt) {
        int rowB = nt*32 + l31;
        int off = rowB*128 + ((gk ^ (rowB & 7)) << 4);
        bf16x8 bfH = *(const bf16x8*)(wHi + off);
        bf16x8 bfL = *(const bf16x8*)(wLo + off);
        acc[nt] = __builtin_amdgcn_mfma_f32_32x32x16_bf16(afH, bfH, acc[nt], 0, 0, 0);
        acc[nt] = __builtin_amdgcn_mfma_f32_32x32x16_bf16(afL, bfH, acc[nt], 0, 0, 0);
        acc[nt] = __builtin_amdgcn_mfma_f32_32x32x16_bf16(afH, bfL, acc[nt], 0, 0, 0);
      }
    }
  }

  int colA[4]; float bia[4], ga[4], be[4];
#pragma unroll
  for (int nt = 0; nt < 4; ++nt) {
    colA[nt] = nt*32 + l31;
    bia[nt] = gb1[colA[nt]]; ga[nt] = glng[colA[nt]]; be[nt] = glnb[colA[nt]];
  }
#pragma unroll
  for (int nt = 0; nt < 4; ++nt)
#pragma unroll
    for (int j = 0; j < 16; ++j) acc[nt][j] += bia[nt];

  __syncthreads();

#pragma unroll
  for (int j = 0; j < 16; ++j) {
    float s = red32(acc[0][j]+acc[1][j]+acc[2][j]+acc[3][j]);
    float q = red32(acc[0][j]*acc[0][j]+acc[1][j]*acc[1][j]
                    +acc[2][j]*acc[2][j]+acc[3][j]*acc[3][j]);
    float mean = s * (1.f/128.f);
    float var = q * (1.f/128.f) - mean*mean;
    float rs = rsqrtf(var + 1e-5f);
    int r = w*32 + (j&3) + 8*(j>>2) + 4*lh5;
    int rsw = r & 31;
#pragma unroll
    for (int nt = 0; nt < 4; ++nt) {
      float v = (acc[nt][j] - mean) * rs * ga[nt] + be[nt];
      v = gelu_fast(v);
      int col = colA[nt], gr = col >> 2;
      *(float*)(gReg + r*512 + ((gr ^ rsw) << 4) + (col & 3)*4) = v;
    }
  }
  __syncthreads();

  {
    int token = tid & 255, half = tid >> 8;
    int tsw = token & 31;
    float lacc[8];
#pragma unroll
    for (int e = 0; e < 8; ++e) lacc[e] = 0.f;
    for (int gr = 0; gr < 16; ++gr) {
      int grr = half*16 + gr;
      f32x4 g4 = *(const f32x4*)(gReg + token*512 + ((grr ^ tsw) << 4));
      const float* wb = w2l + grr*32;
#pragma unroll
      for (int cc = 0; cc < 4; ++cc)
#pragma unroll
        for (int e = 0; e < 8; ++e) lacc[e] = fmaf(g4[cc], wb[cc*8 + e], lacc[e]);
    }
    f32x4 p0 = {lacc[0], lacc[1], lacc[2], lacc[3]};
    f32x4 p1 = {lacc[4], lacc[5], lacc[6], lacc[7]};
    *(f32x4*)(scr + token*20 + half*8)     = p0;
    *(f32x4*)(scr + token*20 + half*8 + 4) = p1;
  }
  __syncthreads();
  if (tid == 0) *refN = 0;
  if (tid < 8) lh[tid] = 0;
  __syncthreads();

  int code = 0; float g0 = 0.f, g1 = 0.f;
  if (tid < 256) {
    float Tc = fminf(fmaxf(temp[0], 0.5f), 5.0f);
    float v[8];
#pragma unroll
    for (int e = 0; e < 8; ++e)
      v[e] = (scr[tid*20 + e] + scr[tid*20 + 8 + e] + gb2v[e]) / Tc;
    int i0 = 0; float b0 = v[0];
#pragma unroll
    for (int e = 1; e < 8; ++e) if (v[e] > b0) { b0 = v[e]; i0 = e; }
    int i1 = -1; float b1 = -3.4e38f;
#pragma unroll
    for (int e = 0; e < 8; ++e) if (e != i0 && v[e] > b1) { b1 = v[e]; i1 = e; }
    float v2 = -3.4e38f;
#pragma unroll
    for (int e = 0; e < 8; ++e) if (e != i0 && e != i1 && v[e] > v2) v2 = v[e];
    float a1 = expf(b1 - b0);
    float s = 1.0f + a1;
    g0 = 1.0f / s; g1 = a1 / s;
    float tt = g0 + g1;
    g0 /= (tt + 1e-10f); g1 /= (tt + 1e-10f);
    code = i0 | (i1 << 4);
    if (b1 - v2 < TAU) {
      int p = atomicAdd(refN, 1);
      refl[p] = tid;
    }
  }
  __syncthreads();

  // ---- in-block refine: wave w handles near-tie token refl[rr] (exact fp32) -
  const int nr = *refN;
  for (int rr = w; rr < nr; rr += 8) {
    int lt = refl[rr] & 0xffff;
    int t = n0 + lt;
    float a0 = gb1[l], a1 = gb1[l + 64];
    const float* xr = x + (size_t)t * 256;
    for (int k = 0; k < 256; k += 4) {
      f32x4 xv = *(const f32x4*)(xr + k);
#pragma unroll
      for (int u = 0; u < 4; ++u) {
        a0 = fmaf(xv[u], gW1[(size_t)(k+u)*128 + l], a0);
        a1 = fmaf(xv[u], gW1[(size_t)(k+u)*128 + 64 + l], a1);
      }
    }
    float s = a0 + a1, q = a0*a0 + a1*a1;
#pragma unroll
    for (int m = 1; m <= 32; m <<= 1) { s += __shfl_xor(s, m); q += __shfl_xor(q, m); }
    float mean = s * (1.f/128.f);
    float var = q * (1.f/128.f) - mean*mean;
    float rs = rsqrtf(var + 1e-5f);
    float g0v = gelu_erf((a0 - mean) * rs * glng[l] + glnb[l]);
    float g1v = gelu_erf((a1 - mean) * rs * glng[l + 64] + glnb[l + 64]);
    float lg[8];
#pragma unroll
    for (int e = 0; e < 8; ++e) {
      float p = g0v * gW2[l*8 + e] + g1v * gW2[(l + 64)*8 + e];
#pragma unroll
      for (int m = 1; m <= 32; m <<= 1) p += __shfl_xor(p, m);
      lg[e] = p;
    }
    if (l == 0) {
      float Tc = fminf(fmaxf(temp[0], 0.5f), 5.0f);
#pragma unroll
      for (int e = 0; e < 8; ++e) lg[e] = (lg[e] + gb2v[e]) / Tc;
      int i0 = 0; float b0 = lg[0];
#pragma unroll
      for (int e = 1; e < 8; ++e) if (lg[e] > b0) { b0 = lg[e]; i0 = e; }
      int i1 = -1; float b1 = -3.4e38f;
#pragma unroll
      for (int e = 0; e < 8; ++e) if (e != i0 && lg[e] > b1) { b1 = lg[e]; i1 = e; }
      float aa = expf(b1 - b0);
      float ss = 1.0f + aa;
      float r0 = 1.0f / ss, r1 = aa / ss;
      float tt = r0 + r1;
      r0 /= (tt + 1e-10f); r1 /= (tt + 1e-10f);
      refl[rr] = lt | ((i0 | (i1 << 4)) << 16);
      refG[rr] = make_float2(r0, r1);
    }
  }
  __syncthreads();

  // ---- scatter: block histogram -> global cnt reservation -> list writes ----
  int si0 = 0, si1 = 0, sp0 = 0, sp1 = 0;
  if (tid < 256) {
    for (int rr = 0; rr < nr; ++rr) {
      if ((refl[rr] & 0xffff) == tid) {
        code = refl[rr] >> 16;
        float2 G = refG[rr];
        g0 = G.x; g1 = G.y;
      }
    }
    rg[n0 + tid] = make_float2(g0, g1);
    si0 = code & 15; si1 = (code >> 4) & 15;
    sp0 = atomicAdd(&lh[si0], 1);
    sp1 = atomicAdd(&lh[si1], 1);
  }
  __syncthreads();
  if (tid < 8) gbase[tid] = lh[tid] ? atomicAdd(cnt + tid, lh[tid]) : 0;
  __syncthreads();
  if (tid < 256) {
    int n = n0 + tid;
    list[(size_t)si0*N_TOK + gbase[si0] + sp0] = n;
    list[(size_t)si1*N_TOK + gbase[si1] + sp1] = n | (int)0x80000000;
  }
}

// ---- experts: BM=32, 4 waves, 8 blocks/CU, pure-VALU LN partials ------------
__global__ __launch_bounds__(256, 8) void expert_kernel(
    const float* __restrict__ x,
    const u16* __restrict__ w1f, const u16* __restrict__ w2f, const u16* __restrict__ w3f,
    const int* __restrict__ cnt, const int* __restrict__ list, const float2* __restrict__ rg,
    const float* __restrict__ eb1, const float* __restrict__ g1v, const float* __restrict__ b1v,
    const float* __restrict__ eb2, const float* __restrict__ g2v, const float* __restrict__ b2v,
    const float* __restrict__ eb3, float* __restrict__ outp)
{
  extern __shared__ char smem[];
  char*  lds0  = smem;                    // 16KB: X/H1 [32][32][16B]; H2 [32][16][16B]
  float* partS = (float*)(smem + 16384);  // [32][8] half-partials
  float* partQ = partS + 256;             // [32][8]
  float* meanv = partQ + 256;             // [32]
  float* rsv   = meanv + 32;
  int*   tokI  = (int*)(rsv + 32);        // [32]
  float* tokW  = (float*)(tokI + 32);     // [32]

  // inline tile map: (e, tix) from cnt[8] prefix (scalar, 8 iters)
  int tix = blockIdx.x;
  int e = -1, count = 0;
#pragma unroll
  for (int i = 0; i < 8; ++i) {
    int ci = cnt[i];
    int nt = (ci + BM - 1) >> 5;
    if (e < 0) {
      if (tix < nt) { e = i; count = ci; }
      else tix -= nt;
    }
  }
  if (e < 0) return;
  const int base = tix * BM;
  const int nvalid = min(BM, count - base);

  const int tid = threadIdx.x;
  const int w = tid >> 6, l = tid & 63;
  const int l31 = l & 31, lh = l >> 5;
  const int h16 = (l31 >> 4) & 1;
  const int rowA = l31;
  const int swA = rowA & 7;

  if (tid < BM) {
    int raw = 0; float wgt = 0.f;
    if (tid < nvalid) {
      raw = list[(size_t)e*N_TOK + base + tid];
      float2 rr = rg[raw & 0x7fffffff];
      wgt = (raw < 0) ? rr.y : rr.x;
    }
    tokI[tid] = raw; tokW[tid] = wgt;
  }
  __syncthreads();

#pragma unroll
  for (int it = 0; it < 4; ++it) {        // stage X: 32 rows x 32 granules
    int G = tid + 256*it;
    int row = G >> 5, g = G & 31;
    int tok = tokI[row] & 0x7fffffff;
    const float* src = x + (size_t)tok*256 + g*8;
    f32x4 va = *(const f32x4*)src;
    f32x4 vb = *(const f32x4*)(src + 4);
    uint4 pk;
    pk.x = cvtpk(va.x, va.y); pk.y = cvtpk(va.z, va.w);
    pk.z = cvtpk(vb.x, vb.y); pk.w = cvtpk(vb.z, vb.w);
    *(uint4*)(lds0 + row*512 + ((g ^ (row & 7)) << 4)) = pk;
  }
  __syncthreads();

  // ---- L1: [32x256] = X @ W1; wave w covers cols [w*64, w*64+64) ------------
  const u16* w1e = w1f + (size_t)e*65536 + (size_t)(w*2)*8192 + l*8;
  f32x16 acc0 = (f32x16)0.f, acc1 = (f32x16)0.f;
  __builtin_amdgcn_s_setprio(1);
#pragma unroll 4
  for (int ks = 0; ks < 16; ++ks) {
    int gk = ks*2 + lh;
    bf16x8 af = *(const bf16x8*)(lds0 + rowA*512 + ((gk ^ swA) << 4));
    bf16x8 b0 = *(const bf16x8*)(w1e + ks*512);
    bf16x8 b1 = *(const bf16x8*)(w1e + 8192 + ks*512);
    acc0 = __builtin_amdgcn_mfma_f32_32x32x16_bf16(af, b0, acc0, 0, 0, 0);
    acc1 = __builtin_amdgcn_mfma_f32_32x32x16_bf16(af, b1, acc1, 0, 0, 0);
  }
  __builtin_amdgcn_s_setprio(0);
  const int colA0 = w*64 + l31, colA1 = colA0 + 32;
  {
    float cb0 = eb1[e*256 + colA0], cb1 = eb1[e*256 + colA1];
#pragma unroll
    for (int j = 0; j < 16; ++j) { acc0[j] += cb0; acc1[j] += cb1; }
  }

#pragma unroll
  for (int j = 0; j < 16; ++j) {          // LN1 half-partials (pure VALU DPP)
    float s = red16(acc0[j] + acc1[j]);
    float q = red16(fmaf(acc0[j], acc0[j], acc1[j]*acc1[j]));
    if ((l & 15) == 0) {
      int r = (j&3) + 8*(j>>2) + 4*lh;
      partS[r*8 + w*2 + h16] = s;
      partQ[r*8 + w*2 + h16] = q;
    }
  }
  __syncthreads();
  if (tid < 32) {
    float s = partS[tid*8]+partS[tid*8+1]+partS[tid*8+2]+partS[tid*8+3]
            + partS[tid*8+4]+partS[tid*8+5]+partS[tid*8+6]+partS[tid*8+7];
    float q = partQ[tid*8]+partQ[tid*8+1]+partQ[tid*8+2]+partQ[tid*8+3]
            + partQ[tid*8+4]+partQ[tid*8+5]+partQ[tid*8+6]+partQ[tid*8+7];
    float m = s * (1.f/256.f);
    float var = q * (1.f/256.f) - m*m;
    meanv[tid] = m; rsv[tid] = rsqrtf(var + 1e-5f);
  }
  __syncthreads();

  {                                       // H1 = gelu(LN1) -> lds0 (b16 stores)
    float ga0 = g1v[e*256 + colA0], bb0 = b1v[e*256 + colA0];
    float ga1 = g1v[e*256 + colA1], bb1 = b1v[e*256 + colA1];
#pragma unroll
    for (int j = 0; j < 16; ++j) {
      int r = (j&3) + 8*(j>>2) + 4*lh;
      float mn = meanv[r], rsx = rsv[r];
      float v0 = gelu_fast3((acc0[j] - mn) * rsx * ga0 + bb0);
      float v1 = gelu_fast3((acc1[j] - mn) * rsx * ga1 + bb1);
      unsigned pk = cvtpk(v0, v1);
      int swz = (r & 7) << 4;
      *(u16*)(lds0 + r*512 + ((colA0*2) ^ swz)) = (u16)pk;
      *(u16*)(lds0 + r*512 + ((colA1*2) ^ swz)) = (u16)(pk >> 16);
    }
  }
  __syncthreads();

  // ---- L2: [32x128] = H1 @ W2; wave w covers cols [w*32, w*32+32) -----------
  const u16* w2e = w2f + (size_t)e*32768 + (size_t)w*8192 + l*8;
  f32x16 accB = (f32x16)0.f;
  __builtin_amdgcn_s_setprio(1);
#pragma unroll 4
  for (int ks = 0; ks < 16; ++ks) {
    int gk = ks*2 + lh;
    bf16x8 af = *(const bf16x8*)(lds0 + rowA*512 + ((gk ^ swA) << 4));
    bf16x8 bf = *(const bf16x8*)(w2e + ks*512);
    accB = __builtin_amdgcn_mfma_f32_32x32x16_bf16(af, bf, accB, 0, 0, 0);
  }
  __builtin_amdgcn_s_setprio(0);
  const int colB = w*32 + l31;
  {
    float cb2 = eb2[e*128 + colB];
#pragma unroll
    for (int j = 0; j < 16; ++j) accB[j] += cb2;
  }

#pragma unroll
  for (int j = 0; j < 16; ++j) {          // LN2 half-partials (pure VALU DPP)
    float s = red16(accB[j]);
    float q = red16(accB[j]*accB[j]);
    if ((l & 15) == 0) {
      int r = (j&3) + 8*(j>>2) + 4*lh;
      partS[r*8 + w*2 + h16] = s;
      partQ[r*8 + w*2 + h16] = q;
    }
  }
  __syncthreads();
  if (tid < 32) {
    float s = partS[tid*8]+partS[tid*8+1]+partS[tid*8+2]+partS[tid*8+3]
            + partS[tid*8+4]+partS[tid*8+5]+partS[tid*8+6]+partS[tid*8+7];
    float q = partQ[tid*8]+partQ[tid*8+1]+partQ[tid*8+2]+partQ[tid*8+3]
            + partQ[tid*8+4]+partQ[tid*8+5]+partQ[tid*8+6]+partQ[tid*8+7];
    float m = s * (1.f/128.f);
    float var = q * (1.f/128.f) - m*m;
    meanv[tid] = m; rsv[tid] = rsqrtf(var + 1e-5f);
  }
  __syncthreads();
  {                                       // H2 = gelu(LN2) -> lds0 (b16 stores)
    float ga2 = g2v[e*128 + colB], bb2 = b2v[e*128 + colB];
#pragma unroll
    for (int j = 0; j < 16; j += 2) {
      int r0 = (j&3) + 8*(j>>2) + 4*lh;
      int r1 = r0 + 1;
      float v0 = gelu_fast3((accB[j]   - meanv[r0]) * rsv[r0] * ga2 + bb2);
      float v1 = gelu_fast3((accB[j+1] - meanv[r1]) * rsv[r1] * ga2 + bb2);
      unsigned pk = cvtpk(v0, v1);
      *(u16*)(lds0 + r0*256 + ((colB*2) ^ ((r0 & 7) << 4))) = (u16)pk;
      *(u16*)(lds0 + r1*256 + ((colB*2) ^ ((r1 & 7) << 4))) = (u16)(pk >> 16);
    }
  }
  __syncthreads();

  if (w == 0) {                           // ---- L3: eo = H2 @ W3 (+b3) -------
    const u16* w3e = w3f + (size_t)e*4096 + l*8;
    f32x16 accC = (f32x16)0.f;
    __builtin_amdgcn_s_setprio(1);
#pragma unroll
    for (int ks = 0; ks < 8; ++ks) {
      int gk = ks*2 + lh;
      bf16x8 af = *(const bf16x8*)(lds0 + rowA*256 + ((gk ^ swA) << 4));
      bf16x8 bf = *(const bf16x8*)(w3e + ks*512);
      accC = __builtin_amdgcn_mfma_f32_32x32x16_bf16(af, bf, accC, 0, 0, 0);
    }
    __builtin_amdgcn_s_setprio(0);
    float b3 = (l31 < 10) ? eb3[e*10 + l31] : 0.f;
#pragma unroll
    for (int j = 0; j < 16; ++j) {
      int rl = (j&3) + 8*(j>>2) + 4*lh;
      if (rl < nvalid && l31 < 10) {
        int raw = tokI[rl];
        int tok = raw & 0x7fffffff;
        float val = (accC[j] + b3) * tokW[rl];
        atomicAdd(outp + (size_t)tok*10 + l31, val);
      }
    }
  }
}

extern "C" void kernel_launch(void* const* d_in, const int* in_sizes, int n_in,
                              void* d_out, int out_size, void* d_ws, size_t ws_size,
                              hipStream_t stream) {
  const float* x     = (const float*)d_in[0];
  const float* gW1   = (const float*)d_in[1];
  const float* gb1   = (const float*)d_in[2];
  const float* glng  = (const float*)d_in[3];
  const float* glnb  = (const float*)d_in[4];
  const float* gW2   = (const float*)d_in[5];
  const float* gb2   = (const float*)d_in[6];
  const float* temp  = (const float*)d_in[7];
  const float* eW1   = (const float*)d_in[8];
  const float* eb1   = (const float*)d_in[9];
  const float* elng1 = (const float*)d_in[10];
  const float* elnb1 = (const float*)d_in[11];
  const float* eW2   = (const float*)d_in[12];
  const float* eb2   = (const float*)d_in[13];
  const float* elng2 = (const float*)d_in[14];
  const float* elnb2 = (const float*)d_in[15];
  const float* eW3   = (const float*)d_in[16];
  const float* eb3   = (const float*)d_in[17];

  char* ws = (char*)d_ws;
  int*    cnt     = (int*)(ws + O_CNT);           // [8]
  float2* rgp     = (float2*)(ws + O_RG);
  int*    list    = (int*)(ws + O_LIST);
  u16*    w1f     = (u16*)(ws + O_W1);
  u16*    w2f     = (u16*)(ws + O_W2);
  u16*    w3f     = (u16*)(ws + O_W3);
  u16*    w1g     = (u16*)(ws + O_W1G);

  hipMemsetAsync(ws, 0, 256, stream);
  hipMemsetAsync(d_out, 0, (size_t)out_size * 4, stream);

  prep_kernel<<<432, 256, 0, stream>>>(eW1, eW2, eW3, gW1, w1f, w2f, w3f, w1g);

  int gate_smem = 155648;
  hipFuncSetAttribute((const void*)gate_kernel,
                      hipFuncAttributeMaxDynamicSharedMemorySize, gate_smem);
  gate_kernel<<<512, 512, gate_smem, stream>>>(x, w1g, gW1, gb1, glng, glnb,
                                               gW2, gb2, temp, rgp, cnt, list);

  int exp_smem = 18944;
  expert_kernel<<<8224, 256, exp_smem, stream>>>(
      x, w1f, w2f, w3f, cnt, list, rgp,
      eb1, elng1, elnb1, eb2, elng2, elnb2, eb3, (float*)d_out);
}

// Round 16
// 248.228 us; speedup vs baseline: 1.0193x; 1.0193x over previous
//
#include <hip/hip_runtime.h>
#include <hip/hip_bf16.h>

#define N_TOK 131072
#define NE 8
#define NOUT 10
#define BM 32
#define TAU 1e-4f

typedef float f32x4 __attribute__((ext_vector_type(4)));
typedef float f32x16 __attribute__((ext_vector_type(16)));
typedef __bf16 bf16x8 __attribute__((ext_vector_type(8)));
typedef unsigned short u16;
typedef unsigned short u16x8 __attribute__((ext_vector_type(8)));

// ws layout (bytes): mandatory ~6.8MB (< proven-safe 7.9MB)
static constexpr size_t O_CNT  = 0;                                // cnt[8]
static constexpr size_t O_RG   = 256;                              // N*8
static constexpr size_t O_LIST = O_RG + (size_t)N_TOK*8;           // 8N*4 sparse segs
static constexpr size_t O_W1   = O_LIST + 8ull*N_TOK*4;            // 1MB
static constexpr size_t O_W2   = O_W1 + 8ull*256*256*2;            // 512KB
static constexpr size_t O_W3   = O_W2 + 8ull*128*256*2;            // 64KB
static constexpr size_t O_W1G  = O_W3 + 8ull*32*128*2;             // 128KB

static __device__ __forceinline__ u16 f2bf(float f) {
  union { float f; unsigned u; } v; v.f = f;
  unsigned r = v.u + 0x7FFFu + ((v.u >> 16) & 1u);
  return (u16)(r >> 16);
}
static __device__ __forceinline__ float bf2f(u16 h) {
  union { unsigned u; float f; } v; v.u = ((unsigned)h) << 16;
  return v.f;
}
static __device__ __forceinline__ unsigned cvtpk(float lo, float hi) {
  unsigned r;
  asm("v_cvt_pk_bf16_f32 %0, %1, %2" : "=v"(r) : "v"(lo), "v"(hi));
  return r;
}
// DPP-based 32-lane sum: 4 VALU-pipe steps + 1 ds_swizzle (vs 5 ds_swizzle).
// Reorders the addition tree (rotate-sum within 16) — fp32-rounding-level only.
template<int CTRL>
static __device__ __forceinline__ float dppadd(float v) {
  int p = __builtin_amdgcn_update_dpp(0, __float_as_int(v), CTRL, 0xF, 0xF, true);
  return v + __int_as_float(p);
}
static __device__ __forceinline__ float red32(float v) {
  v = dppadd<0xB1>(v);    // quad_perm [1,0,3,2]  (xor 1)
  v = dppadd<0x4E>(v);    // quad_perm [2,3,0,1]  (xor 2)
  v = dppadd<0x124>(v);   // row_ror:4
  v = dppadd<0x128>(v);   // row_ror:8  -> all 16 lanes of row hold row sum
  int s = __builtin_amdgcn_ds_swizzle(__float_as_int(v), 0x401F); // xor 16
  return v + __int_as_float(s);
}
static __device__ __forceinline__ float gelu_erf(float v) {
  return 0.5f * v * (1.0f + erff(v * 0.70710678118654752440f));
}
// 4-term A&S 7.1.26 (|erf err|<=1.5e-7) — gate LN epilogue (routing-sensitive)
static __device__ __forceinline__ float gelu_fast(float v) {
  float s = fabsf(v) * 0.70710678118654752440f;
  float t = __builtin_amdgcn_rcpf(fmaf(0.3275911f, s, 1.0f));
  float p = t * fmaf(t, fmaf(t, fmaf(t, fmaf(t, 1.061405429f, -1.453152027f),
                                     1.421413741f), -0.284496736f), 0.254829592f);
  float e = __builtin_amdgcn_exp2f(s * s * -1.44269504088896f);
  float erfa = fmaf(-p, e, 1.0f);
  return fmaf(0.5f * fabsf(v), erfa, 0.5f * v);
}
// 3-term A&S 7.1.25 (|erf err|<=2.5e-5 << bf16 noise) — expert only
static __device__ __forceinline__ float gelu_fast3(float v) {
  float s = fabsf(v) * 0.70710678118654752440f;
  float t = __builtin_amdgcn_rcpf(fmaf(0.47047f, s, 1.0f));
  float p = t * fmaf(t, fmaf(t, 0.7478556f, -0.0958798f), 0.3480242f);
  float e = __builtin_amdgcn_exp2f(s * s * -1.44269504088896f);
  float erfa = fmaf(-p, e, 1.0f);
  return fmaf(0.5f * fabsf(v), erfa, 0.5f * v);
}

// ---- weight prep: fp32 -> bf16 per-MFMA fragment streams --------------------
__global__ __launch_bounds__(256) void prep_kernel(
    const float* __restrict__ eW1, const float* __restrict__ eW2,
    const float* __restrict__ eW3, const float* __restrict__ gW1,
    u16* __restrict__ w1f, u16* __restrict__ w2f, u16* __restrict__ w3f,
    u16* __restrict__ w1g)
{
  int id = blockIdx.x * 256 + threadIdx.x;
  u16x8 pk;
  if (id < 65536) {                       // expert W1: 8e x 8nt x 16ks x 64l
    int e = id >> 13, rem = id & 8191;
    int l = rem & 63;
    int n = ((rem >> 10) & 7)*32 + (l & 31);
    int k0 = (((rem >> 6) & 15)*2 + (l >> 5)) * 8;
#pragma unroll
    for (int j = 0; j < 8; ++j) pk[j] = f2bf(eW1[((size_t)(e*256 + k0 + j))*256 + n]);
    *(u16x8*)(w1f + (size_t)id*8) = pk;
  } else if (id < 98304) {                // expert W2: 8e x 4nt x 16ks x 64l
    int id2 = id - 65536;
    int e = id2 >> 12, rem = id2 & 4095;
    int l = rem & 63;
    int n = ((rem >> 10) & 3)*32 + (l & 31);
    int k0 = (((rem >> 6) & 15)*2 + (l >> 5)) * 8;
#pragma unroll
    for (int j = 0; j < 8; ++j) pk[j] = f2bf(eW2[((size_t)(e*256 + k0 + j))*128 + n]);
    *(u16x8*)(w2f + (size_t)id2*8) = pk;
  } else if (id < 102400) {               // expert W3 padded: 8e x 8ks x 64l
    int id3 = id - 98304;
    int e = id3 >> 9, ks = (id3 >> 6) & 7, l = id3 & 63;
    int n = l & 31;
    int k0 = (ks*2 + (l >> 5)) * 8;
#pragma unroll
    for (int j = 0; j < 8; ++j) {
      float v = (n < 10) ? eW3[((size_t)(e*128 + k0 + j))*10 + n] : 0.f;
      pk[j] = f2bf(v);
    }
    *(u16x8*)(w3f + (size_t)id3*8) = pk;
  } else {                                // gate W1 split hi/lo
    int id4 = id - 102400;                // 8192 ids
    int gp = id4 & 7, r = (id4 >> 3) & 127, c = (id4 >> 10) & 3, pl = id4 >> 12;
    int k0 = c*64 + ((gp ^ (r & 7)) * 8);
#pragma unroll
    for (int j = 0; j < 8; ++j) {
      float v = gW1[(size_t)(k0 + j)*128 + r];
      u16 hi = f2bf(v);
      if (pl == 0) pk[j] = hi;
      else         pk[j] = f2bf(v - bf2f(hi));
    }
    *(u16x8*)(w1g + ((size_t)(pl*4 + c)*128 + r)*64 + gp*8) = pk;
  }
}

// ---- gate: split-bf16 MFMA + LN + gelu + logits + top2 + in-block refine ----
__global__ __launch_bounds__(512) void gate_kernel(
    const float* __restrict__ x, const u16* __restrict__ w1g,
    const float* __restrict__ gW1,
    const float* __restrict__ gb1, const float* __restrict__ glng,
    const float* __restrict__ glnb, const float* __restrict__ gW2,
    const float* __restrict__ gb2v, const float* __restrict__ temp,
    float2* __restrict__ rg, int* __restrict__ cnt, int* __restrict__ list)
{
  extern __shared__ char gsm[];
  char* aHi = gsm;                        // [256 rows][8 gran][16B] 32KB
  char* aLo = gsm + 32768;
  char* wHi = gsm + 65536;                // [128 rows][8 gran][16B] 16KB
  char* wLo = gsm + 81920;
  char* gReg = gsm;                       // logits phase: [256][32 gran][16B] 128KB
  float* scr = (float*)(gsm + 131072);    // [256][20]
  float* w2l = (float*)(gsm + 151552);    // [128][8] = 4KB (reused by refine arrays)
  int*    refN = (int*)(gsm + 151552);    // after logits: refine scratch
  int*    refl = (int*)(gsm + 151560);    // [256]
  float2* refG = (float2*)(gsm + 152584); // [256]
  __shared__ int lh[8], gbase[8];

  const int tid = threadIdx.x;
  const int n0 = blockIdx.x * 256;
  const int w = tid >> 6, l = tid & 63;
  const int l31 = l & 31, lh5 = l >> 5;

  for (int i = tid; i < 1024; i += 512) w2l[i] = gW2[i];

  f32x16 acc[4];
#pragma unroll
  for (int nt = 0; nt < 4; ++nt) acc[nt] = (f32x16)0.f;

  const int rowA = w*32 + l31;
  const int swA = rowA & 7;

  for (int c = 0; c < 4; ++c) {
    __syncthreads();
#pragma unroll
    for (int it = 0; it < 4; ++it) {
      int G = tid + 512*it;
      int row = G >> 3, g = G & 7;
      const float* src = x + (size_t)(n0 + row)*256 + c*64 + g*8;
      f32x4 va = *(const f32x4*)src;
      f32x4 vb = *(const f32x4*)(src + 4);
      u16x8 hi, lo;
#pragma unroll
      for (int i = 0; i < 4; ++i) {
        u16 h = f2bf(va[i]); hi[i] = h; lo[i] = f2bf(va[i] - bf2f(h));
      }
#pragma unroll
      for (int i = 0; i < 4; ++i) {
        u16 h = f2bf(vb[i]); hi[4+i] = h; lo[4+i] = f2bf(vb[i] - bf2f(h));
      }
      int off = row*128 + ((g ^ (row & 7)) << 4);
      *(u16x8*)(aHi + off) = hi;
      *(u16x8*)(aLo + off) = lo;
    }
    {
      const u16* srcH = w1g + (size_t)c*8192;
      const u16* srcL = w1g + (size_t)(4 + c)*8192;
#pragma unroll
      for (int it = 0; it < 2; ++it) {
        int i = tid + 512*it;
        *(u16x8*)(wHi + i*16) = *(const u16x8*)(srcH + i*8);
        *(u16x8*)(wLo + i*16) = *(const u16x8*)(srcL + i*8);
      }
    }
    __syncthreads();
#pragma unroll
    for (int ks = 0; ks < 4; ++ks) {
      int gk = ks*2 + lh5;
      bf16x8 afH = *(const bf16x8*)(aHi + rowA*128 + ((gk ^ swA) << 4));
      bf16x8 afL = *(const bf16x8*)(aLo + rowA*128 + ((gk ^ swA) << 4));
#pragma unroll
      for (int nt = 0; nt < 4; ++nt) {
        int rowB = nt*32 + l31;
        int off = rowB*128 + ((gk ^ (rowB & 7)) << 4);
        bf16x8 bfH = *(const bf16x8*)(wHi + off);
        bf16x8 bfL = *(const bf16x8*)(wLo + off);
        acc[nt] = __builtin_amdgcn_mfma_f32_32x32x16_bf16(afH, bfH, acc[nt], 0, 0, 0);
        acc[nt] = __builtin_amdgcn_mfma_f32_32x32x16_bf16(afL, bfH, acc[nt], 0, 0, 0);
        acc[nt] = __builtin_amdgcn_mfma_f32_32x32x16_bf16(afH, bfL, acc[nt], 0, 0, 0);
      }
    }
  }

  int colA[4]; float bia[4], ga[4], be[4];
#pragma unroll
  for (int nt = 0; nt < 4; ++nt) {
    colA[nt] = nt*32 + l31;
    bia[nt] = gb1[colA[nt]]; ga[nt] = glng[colA[nt]]; be[nt] = glnb[colA[nt]];
  }
#pragma unroll
  for (int nt = 0; nt < 4; ++nt)
#pragma unroll
    for (int j = 0; j < 16; ++j) acc[nt][j] += bia[nt];

  __syncthreads();

#pragma unroll
  for (int j = 0; j < 16; ++j) {
    float s = red32(acc[0][j]+acc[1][j]+acc[2][j]+acc[3][j]);
    float q = red32(acc[0][j]*acc[0][j]+acc[1][j]*acc[1][j]
                    +acc[2][j]*acc[2][j]+acc[3][j]*acc[3][j]);
    float mean = s * (1.f/128.f);
    float var = q * (1.f/128.f) - mean*mean;
    float rs = rsqrtf(var + 1e-5f);
    int r = w*32 + (j&3) + 8*(j>>2) + 4*lh5;
    int rsw = r & 31;
#pragma unroll
    for (int nt = 0; nt < 4; ++nt) {
      float v = (acc[nt][j] - mean) * rs * ga[nt] + be[nt];
      v = gelu_fast(v);
      int col = colA[nt], gr = col >> 2;
      *(float*)(gReg + r*512 + ((gr ^ rsw) << 4) + (col & 3)*4) = v;
    }
  }
  __syncthreads();

  {
    int token = tid & 255, half = tid >> 8;
    int tsw = token & 31;
    float lacc[8];
#pragma unroll
    for (int e = 0; e < 8; ++e) lacc[e] = 0.f;
    for (int gr = 0; gr < 16; ++gr) {
      int grr = half*16 + gr;
      f32x4 g4 = *(const f32x4*)(gReg + token*512 + ((grr ^ tsw) << 4));
      const float* wb = w2l + grr*32;
#pragma unroll
      for (int cc = 0; cc < 4; ++cc)
#pragma unroll
        for (int e = 0; e < 8; ++e) lacc[e] = fmaf(g4[cc], wb[cc*8 + e], lacc[e]);
    }
    f32x4 p0 = {lacc[0], lacc[1], lacc[2], lacc[3]};
    f32x4 p1 = {lacc[4], lacc[5], lacc[6], lacc[7]};
    *(f32x4*)(scr + token*20 + half*8)     = p0;
    *(f32x4*)(scr + token*20 + half*8 + 4) = p1;
  }
  __syncthreads();
  if (tid == 0) *refN = 0;
  if (tid < 8) lh[tid] = 0;
  __syncthreads();

  int code = 0; float g0 = 0.f, g1 = 0.f;
  if (tid < 256) {
    float Tc = fminf(fmaxf(temp[0], 0.5f), 5.0f);
    float v[8];
#pragma unroll
    for (int e = 0; e < 8; ++e)
      v[e] = (scr[tid*20 + e] + scr[tid*20 + 8 + e] + gb2v[e]) / Tc;
    int i0 = 0; float b0 = v[0];
#pragma unroll
    for (int e = 1; e < 8; ++e) if (v[e] > b0) { b0 = v[e]; i0 = e; }
    int i1 = -1; float b1 = -3.4e38f;
#pragma unroll
    for (int e = 0; e < 8; ++e) if (e != i0 && v[e] > b1) { b1 = v[e]; i1 = e; }
    float v2 = -3.4e38f;
#pragma unroll
    for (int e = 0; e < 8; ++e) if (e != i0 && e != i1 && v[e] > v2) v2 = v[e];
    float a1 = expf(b1 - b0);
    float s = 1.0f + a1;
    g0 = 1.0f / s; g1 = a1 / s;
    float tt = g0 + g1;
    g0 /= (tt + 1e-10f); g1 /= (tt + 1e-10f);
    code = i0 | (i1 << 4);
    if (b1 - v2 < TAU) {
      int p = atomicAdd(refN, 1);
      refl[p] = tid;
    }
  }
  __syncthreads();

  // ---- in-block refine: wave w handles near-tie token refl[rr] (exact fp32) -
  const int nr = *refN;
  for (int rr = w; rr < nr; rr += 8) {
    int lt = refl[rr] & 0xffff;
    int t = n0 + lt;
    float a0 = gb1[l], a1 = gb1[l + 64];
    const float* xr = x + (size_t)t * 256;
    for (int k = 0; k < 256; k += 4) {
      f32x4 xv = *(const f32x4*)(xr + k);
#pragma unroll
      for (int u = 0; u < 4; ++u) {
        a0 = fmaf(xv[u], gW1[(size_t)(k+u)*128 + l], a0);
        a1 = fmaf(xv[u], gW1[(size_t)(k+u)*128 + 64 + l], a1);
      }
    }
    float s = a0 + a1, q = a0*a0 + a1*a1;
#pragma unroll
    for (int m = 1; m <= 32; m <<= 1) { s += __shfl_xor(s, m); q += __shfl_xor(q, m); }
    float mean = s * (1.f/128.f);
    float var = q * (1.f/128.f) - mean*mean;
    float rs = rsqrtf(var + 1e-5f);
    float g0v = gelu_erf((a0 - mean) * rs * glng[l] + glnb[l]);
    float g1v = gelu_erf((a1 - mean) * rs * glng[l + 64] + glnb[l + 64]);
    float lg[8];
#pragma unroll
    for (int e = 0; e < 8; ++e) {
      float p = g0v * gW2[l*8 + e] + g1v * gW2[(l + 64)*8 + e];
#pragma unroll
      for (int m = 1; m <= 32; m <<= 1) p += __shfl_xor(p, m);
      lg[e] = p;
    }
    if (l == 0) {
      float Tc = fminf(fmaxf(temp[0], 0.5f), 5.0f);
#pragma unroll
      for (int e = 0; e < 8; ++e) lg[e] = (lg[e] + gb2v[e]) / Tc;
      int i0 = 0; float b0 = lg[0];
#pragma unroll
      for (int e = 1; e < 8; ++e) if (lg[e] > b0) { b0 = lg[e]; i0 = e; }
      int i1 = -1; float b1 = -3.4e38f;
#pragma unroll
      for (int e = 0; e < 8; ++e) if (e != i0 && lg[e] > b1) { b1 = lg[e]; i1 = e; }
      float aa = expf(b1 - b0);
      float ss = 1.0f + aa;
      float r0 = 1.0f / ss, r1 = aa / ss;
      float tt = r0 + r1;
      r0 /= (tt + 1e-10f); r1 /= (tt + 1e-10f);
      refl[rr] = lt | ((i0 | (i1 << 4)) << 16);
      refG[rr] = make_float2(r0, r1);
    }
  }
  __syncthreads();

  // ---- scatter: block histogram -> global cnt reservation -> list writes ----
  int si0 = 0, si1 = 0, sp0 = 0, sp1 = 0;
  if (tid < 256) {
    for (int rr = 0; rr < nr; ++rr) {
      if ((refl[rr] & 0xffff) == tid) {
        code = refl[rr] >> 16;
        float2 G = refG[rr];
        g0 = G.x; g1 = G.y;
      }
    }
    rg[n0 + tid] = make_float2(g0, g1);
    si0 = code & 15; si1 = (code >> 4) & 15;
    sp0 = atomicAdd(&lh[si0], 1);
    sp1 = atomicAdd(&lh[si1], 1);
  }
  __syncthreads();
  if (tid < 8) gbase[tid] = lh[tid] ? atomicAdd(cnt + tid, lh[tid]) : 0;
  __syncthreads();
  if (tid < 256) {
    int n = n0 + tid;
    list[(size_t)si0*N_TOK + gbase[si0] + sp0] = n;
    list[(size_t)si1*N_TOK + gbase[si1] + sp1] = n | (int)0x80000000;
  }
}

// ---- experts: BM=32, 4 waves, 8 blocks/CU, DPP LN reductions, atomic out ----
__global__ __launch_bounds__(256, 8) void expert_kernel(
    const float* __restrict__ x,
    const u16* __restrict__ w1f, const u16* __restrict__ w2f, const u16* __restrict__ w3f,
    const int* __restrict__ cnt, const int* __restrict__ list, const float2* __restrict__ rg,
    const float* __restrict__ eb1, const float* __restrict__ g1v, const float* __restrict__ b1v,
    const float* __restrict__ eb2, const float* __restrict__ g2v, const float* __restrict__ b2v,
    const float* __restrict__ eb3, float* __restrict__ outp)
{
  extern __shared__ char smem[];
  char*  lds0  = smem;                    // 16KB: X/H1 [32][32][16B]; H2 [32][16][16B]
  float* partS = (float*)(smem + 16384);  // [32][4]
  float* partQ = partS + 128;
  float* meanv = partQ + 128;             // [32]
  float* rsv   = meanv + 32;
  int*   tokI  = (int*)(rsv + 32);        // [32]
  float* tokW  = (float*)(tokI + 32);     // [32]

  // inline tile map: (e, tix) from cnt[8] prefix (scalar, 8 iters)
  int tix = blockIdx.x;
  int e = -1, count = 0;
#pragma unroll
  for (int i = 0; i < 8; ++i) {
    int ci = cnt[i];
    int nt = (ci + BM - 1) >> 5;
    if (e < 0) {
      if (tix < nt) { e = i; count = ci; }
      else tix -= nt;
    }
  }
  if (e < 0) return;
  const int base = tix * BM;
  const int nvalid = min(BM, count - base);

  const int tid = threadIdx.x;
  const int w = tid >> 6, l = tid & 63;
  const int l31 = l & 31, lh = l >> 5;
  const int rowA = l31;
  const int swA = rowA & 7;

  if (tid < BM) {
    int raw = 0; float wgt = 0.f;
    if (tid < nvalid) {
      raw = list[(size_t)e*N_TOK + base + tid];
      float2 rr = rg[raw & 0x7fffffff];
      wgt = (raw < 0) ? rr.y : rr.x;
    }
    tokI[tid] = raw; tokW[tid] = wgt;
  }
  __syncthreads();

#pragma unroll
  for (int it = 0; it < 4; ++it) {        // stage X: 32 rows x 32 granules
    int G = tid + 256*it;
    int row = G >> 5, g = G & 31;
    int tok = tokI[row] & 0x7fffffff;
    const float* src = x + (size_t)tok*256 + g*8;
    f32x4 va = *(const f32x4*)src;
    f32x4 vb = *(const f32x4*)(src + 4);
    uint4 pk;
    pk.x = cvtpk(va.x, va.y); pk.y = cvtpk(va.z, va.w);
    pk.z = cvtpk(vb.x, vb.y); pk.w = cvtpk(vb.z, vb.w);
    *(uint4*)(lds0 + row*512 + ((g ^ (row & 7)) << 4)) = pk;
  }
  __syncthreads();

  // ---- L1: [32x256] = X @ W1; wave w covers cols [w*64, w*64+64) ------------
  const u16* w1e = w1f + (size_t)e*65536 + (size_t)(w*2)*8192 + l*8;
  f32x16 acc0 = (f32x16)0.f, acc1 = (f32x16)0.f;
  __builtin_amdgcn_s_setprio(1);
#pragma unroll 4
  for (int ks = 0; ks < 16; ++ks) {
    int gk = ks*2 + lh;
    bf16x8 af = *(const bf16x8*)(lds0 + rowA*512 + ((gk ^ swA) << 4));
    bf16x8 b0 = *(const bf16x8*)(w1e + ks*512);
    bf16x8 b1 = *(const bf16x8*)(w1e + 8192 + ks*512);
    acc0 = __builtin_amdgcn_mfma_f32_32x32x16_bf16(af, b0, acc0, 0, 0, 0);
    acc1 = __builtin_amdgcn_mfma_f32_32x32x16_bf16(af, b1, acc1, 0, 0, 0);
  }
  __builtin_amdgcn_s_setprio(0);
  const int colA0 = w*64 + l31, colA1 = colA0 + 32;
  {
    float cb0 = eb1[e*256 + colA0], cb1 = eb1[e*256 + colA1];
#pragma unroll
    for (int j = 0; j < 16; ++j) { acc0[j] += cb0; acc1[j] += cb1; }
  }

#pragma unroll
  for (int j = 0; j < 16; ++j) {          // LN1 partials (DPP + 1 swizzle)
    float s = red32(acc0[j] + acc1[j]);
    float q = red32(acc0[j]*acc0[j] + acc1[j]*acc1[j]);
    if (l31 == 0) {
      int r = (j&3) + 8*(j>>2) + 4*lh;
      partS[r*4 + w] = s;
      partQ[r*4 + w] = q;
    }
  }
  __syncthreads();
  if (tid < 32) {
    float s = partS[tid*4]+partS[tid*4+1]+partS[tid*4+2]+partS[tid*4+3];
    float q = partQ[tid*4]+partQ[tid*4+1]+partQ[tid*4+2]+partQ[tid*4+3];
    float m = s * (1.f/256.f);
    float var = q * (1.f/256.f) - m*m;
    meanv[tid] = m; rsv[tid] = rsqrtf(var + 1e-5f);
  }
  __syncthreads();

  {                                       // H1 = gelu(LN1) -> lds0 (b16 stores)
    float ga0 = g1v[e*256 + colA0], bb0 = b1v[e*256 + colA0];
    float ga1 = g1v[e*256 + colA1], bb1 = b1v[e*256 + colA1];
#pragma unroll
    for (int j = 0; j < 16; ++j) {
      int r = (j&3) + 8*(j>>2) + 4*lh;
      float mn = meanv[r], rsx = rsv[r];
      float v0 = gelu_fast3((acc0[j] - mn) * rsx * ga0 + bb0);
      float v1 = gelu_fast3((acc1[j] - mn) * rsx * ga1 + bb1);
      unsigned pk = cvtpk(v0, v1);
      int swz = (r & 7) << 4;
      *(u16*)(lds0 + r*512 + ((colA0*2) ^ swz)) = (u16)pk;
      *(u16*)(lds0 + r*512 + ((colA1*2) ^ swz)) = (u16)(pk >> 16);
    }
  }
  __syncthreads();

  // ---- L2: [32x128] = H1 @ W2; wave w covers cols [w*32, w*32+32) -----------
  const u16* w2e = w2f + (size_t)e*32768 + (size_t)w*8192 + l*8;
  f32x16 accB = (f32x16)0.f;
  __builtin_amdgcn_s_setprio(1);
#pragma unroll 4
  for (int ks = 0; ks < 16; ++ks) {
    int gk = ks*2 + lh;
    bf16x8 af = *(const bf16x8*)(lds0 + rowA*512 + ((gk ^ swA) << 4));
    bf16x8 bf = *(const bf16x8*)(w2e + ks*512);
    accB = __builtin_amdgcn_mfma_f32_32x32x16_bf16(af, bf, accB, 0, 0, 0);
  }
  __builtin_amdgcn_s_setprio(0);
  const int colB = w*32 + l31;
  {
    float cb2 = eb2[e*128 + colB];
#pragma unroll
    for (int j = 0; j < 16; ++j) accB[j] += cb2;
  }

#pragma unroll
  for (int j = 0; j < 16; ++j) {          // LN2 partials (DPP + 1 swizzle)
    float s = red32(accB[j]);
    float q = red32(accB[j]*accB[j]);
    if (l31 == 0) {
      int r = (j&3) + 8*(j>>2) + 4*lh;
      partS[r*4 + w] = s;
      partQ[r*4 + w] = q;
    }
  }
  __syncthreads();
  if (tid < 32) {
    float s = partS[tid*4]+partS[tid*4+1]+partS[tid*4+2]+partS[tid*4+3];
    float q = partQ[tid*4]+partQ[tid*4+1]+partQ[tid*4+2]+partQ[tid*4+3];
    float m = s * (1.f/128.f);
    float var = q * (1.f/128.f) - m*m;
    meanv[tid] = m; rsv[tid] = rsqrtf(var + 1e-5f);
  }
  __syncthreads();
  {                                       // H2 = gelu(LN2) -> lds0 (b16 stores)
    float ga2 = g2v[e*128 + colB], bb2 = b2v[e*128 + colB];
#pragma unroll
    for (int j = 0; j < 16; j += 2) {
      int r0 = (j&3) + 8*(j>>2) + 4*lh;
      int r1 = r0 + 1;
      float v0 = gelu_fast3((accB[j]   - meanv[r0]) * rsv[r0] * ga2 + bb2);
      float v1 = gelu_fast3((accB[j+1] - meanv[r1]) * rsv[r1] * ga2 + bb2);
      unsigned pk = cvtpk(v0, v1);
      *(u16*)(lds0 + r0*256 + ((colB*2) ^ ((r0 & 7) << 4))) = (u16)pk;
      *(u16*)(lds0 + r1*256 + ((colB*2) ^ ((r1 & 7) << 4))) = (u16)(pk >> 16);
    }
  }
  __syncthreads();

  if (w == 0) {                           // ---- L3: eo = H2 @ W3 (+b3) -------
    const u16* w3e = w3f + (size_t)e*4096 + l*8;
    f32x16 accC = (f32x16)0.f;
    __builtin_amdgcn_s_setprio(1);
#pragma unroll
    for (int ks = 0; ks < 8; ++ks) {
      int gk = ks*2 + lh;
      bf16x8 af = *(const bf16x8*)(lds0 + rowA*256 + ((gk ^ swA) << 4));
      bf16x8 bf = *(const bf16x8*)(w3e + ks*512);
      accC = __builtin_amdgcn_mfma_f32_32x32x16_bf16(af, bf, accC, 0, 0, 0);
    }
    __builtin_amdgcn_s_setprio(0);
    float b3 = (l31 < 10) ? eb3[e*10 + l31] : 0.f;
#pragma unroll
    for (int j = 0; j < 16; ++j) {
      int rl = (j&3) + 8*(j>>2) + 4*lh;
      if (rl < nvalid && l31 < 10) {
        int raw = tokI[rl];
        int tok = raw & 0x7fffffff;
        float val = (accC[j] + b3) * tokW[rl];
        atomicAdd(outp + (size_t)tok*10 + l31, val);
      }
    }
  }
}

extern "C" void kernel_launch(void* const* d_in, const int* in_sizes, int n_in,
                              void* d_out, int out_size, void* d_ws, size_t ws_size,
                              hipStream_t stream) {
  const float* x     = (const float*)d_in[0];
  const float* gW1   = (const float*)d_in[1];
  const float* gb1   = (const float*)d_in[2];
  const float* glng  = (const float*)d_in[3];
  const float* glnb  = (const float*)d_in[4];
  const float* gW2   = (const float*)d_in[5];
  const float* gb2   = (const float*)d_in[6];
  const float* temp  = (const float*)d_in[7];
  const float* eW1   = (const float*)d_in[8];
  const float* eb1   = (const float*)d_in[9];
  const float* elng1 = (const float*)d_in[10];
  const float* elnb1 = (const float*)d_in[11];
  const float* eW2   = (const float*)d_in[12];
  const float* eb2   = (const float*)d_in[13];
  const float* elng2 = (const float*)d_in[14];
  const float* elnb2 = (const float*)d_in[15];
  const float* eW3   = (const float*)d_in[16];
  const float* eb3   = (const float*)d_in[17];

  char* ws = (char*)d_ws;
  int*    cnt     = (int*)(ws + O_CNT);           // [8]
  float2* rgp     = (float2*)(ws + O_RG);
  int*    list    = (int*)(ws + O_LIST);
  u16*    w1f     = (u16*)(ws + O_W1);
  u16*    w2f     = (u16*)(ws + O_W2);
  u16*    w3f     = (u16*)(ws + O_W3);
  u16*    w1g     = (u16*)(ws + O_W1G);

  hipMemsetAsync(ws, 0, 256, stream);
  hipMemsetAsync(d_out, 0, (size_t)out_size * 4, stream);

  prep_kernel<<<432, 256, 0, stream>>>(eW1, eW2, eW3, gW1, w1f, w2f, w3f, w1g);

  int gate_smem = 155648;
  hipFuncSetAttribute((const void*)gate_kernel,
                      hipFuncAttributeMaxDynamicSharedMemorySize, gate_smem);
  gate_kernel<<<512, 512, gate_smem, stream>>>(x, w1g, gW1, gb1, glng, glnb,
                                               gW2, gb2, temp, rgp, cnt, list);

  int exp_smem = 17920;
  expert_kernel<<<8224, 256, exp_smem, stream>>>(
      x, w1f, w2f, w3f, cnt, list, rgp,
      eb1, elng1, elnb1, eb2, elng2, elnb2, eb3, (float*)d_out);
}